// Round 8
// baseline (387.542 us; speedup 1.0000x reference)
//
#include <hip/hip_runtime.h>
#include <hip/hip_bf16.h>
#include <stdint.h>

typedef float floatx4 __attribute__((ext_vector_type(4)));

// ---------------------------------------------------------------------------
// Threefry-2x32 (JAX-exact): 20 rounds, key injection every 4.
// ---------------------------------------------------------------------------
__host__ __device__ inline uint32_t rotl32(uint32_t x, int r) {
#ifdef __HIP_DEVICE_COMPILE__
  return __builtin_amdgcn_alignbit(x, x, 32 - r);
#else
  return (x << r) | (x >> (32 - r));
#endif
}

__host__ __device__ inline void tf2x32(uint32_t k0, uint32_t k1,
                                       uint32_t x0, uint32_t x1,
                                       uint32_t& o0, uint32_t& o1) {
  const uint32_t k2 = k0 ^ k1 ^ 0x1BD11BDAu;
  x0 += k0; x1 += k1;
#define TFR(r) { x0 += x1; x1 = rotl32(x1, r); x1 ^= x0; }
  TFR(13) TFR(15) TFR(26) TFR(6)
  x0 += k1; x1 += k2 + 1u;
  TFR(17) TFR(29) TFR(16) TFR(24)
  x0 += k2; x1 += k0 + 2u;
  TFR(13) TFR(15) TFR(26) TFR(6)
  x0 += k0; x1 += k1 + 3u;
  TFR(17) TFR(29) TFR(16) TFR(24)
  x0 += k1; x1 += k2 + 4u;
  TFR(13) TFR(15) TFR(26) TFR(6)
  x0 += k2; x1 += k0 + 5u;
#undef TFR
  o0 = x0; o1 = x1;
}

// Partitionable-mode 32-bit random bits, counts (0, i), bits = o0 ^ o1.
// [verified bit-exact vs np ref in rounds 3-6]
__device__ inline uint32_t jax_bits32(uint32_t kA, uint32_t kB, uint32_t i) {
  uint32_t o0, o1;
  tf2x32(kA, kB, 0u, i, o0, o1);
  return o0 ^ o1;
}

__device__ inline float jax_uniform(uint32_t bits) {
  return __uint_as_float((bits >> 9) | 0x3f800000u) - 1.0f;
}

#define D_DIM   4096
#define E_DIM   64
#define EMB     128
#define M_DIM   11008
#define NROWS   4096          // B*S
#define BIN_N   45088768      // NROWS*M_DIM
#define KSPLIT  32            // k-splits in krnA (each 128 wide)
#define CK      32            // staged k-chunk
#define XSTR    286           // k-line stride: 4*286 % 32 == 24 -> 2-way stores (free)
#define WSTR    70            // 4*70 % 32 == 24 -> same

// quad-spread address within a k-line: fragment f = v>>3 at f*8 + (f>>2)*4 so
// the 8 fragments of one wave's b128 read start in 8 distinct bank quads.
__device__ inline int qspread(int v) { return v + ((v >> 5) << 2); }

// ---------------------------------------------------------------------------
// Kernel A: logits partials, transposed-LDS outer-product fp32 GEMM.
// Grid (16 row-blocks, 32 k-splits) x 256 thr.  Block: 256 rows x 64 experts
// over 128 K.  Thread (jc=t&7, rg=t>>3): 8 rows x 8 experts, acc[8][8].
// ---------------------------------------------------------------------------
__global__ __launch_bounds__(256) void krnA(const float* __restrict__ x,
                                            const float* __restrict__ Wr,
                                            float* __restrict__ part) {
  __shared__ __align__(16) float xsT[CK * XSTR];   // 35.8 KB
  __shared__ __align__(16) float wsT[CK * WSTR];   // 8.75 KB
  const int rb = blockIdx.x, ks = blockIdx.y, t = threadIdx.x;
  const int rbase = rb * 256, kbase0 = ks * 128;
  const int jc = t & 7, rg = t >> 3;
  const int xoff = (rg * 8) + ((rg >> 2) << 2);    // qspread of rg*8
  const int woff = (jc * 8) + ((jc >> 2) << 2);
  float acc[8][8] = {};

  for (int c = 0; c < 4; ++c) {
    const int kbase = kbase0 + c * CK;
    // stage x: 256 rows x 32 k (8 float4 / thread, coalesced; 2-way LDS stores)
#pragma unroll
    for (int it = 0; it < 8; ++it) {
      int idx = t + it * 256;
      int row = idx >> 3, kq = idx & 7;
      float4 v = *(const float4*)&x[(size_t)(rbase + row) * D_DIM + kbase + kq * 4];
      int adr = qspread(row);
      xsT[(kq * 4 + 0) * XSTR + adr] = v.x;
      xsT[(kq * 4 + 1) * XSTR + adr] = v.y;
      xsT[(kq * 4 + 2) * XSTR + adr] = v.z;
      xsT[(kq * 4 + 3) * XSTR + adr] = v.w;
    }
    // stage Wr: 64 experts x 32 k (2 float4 / thread)
#pragma unroll
    for (int it = 0; it < 2; ++it) {
      int idx = t + it * 256;
      int e = idx >> 3, kq = idx & 7;
      float4 v = *(const float4*)&Wr[(size_t)e * D_DIM + kbase + kq * 4];
      int adr = qspread(e);
      wsT[(kq * 4 + 0) * WSTR + adr] = v.x;
      wsT[(kq * 4 + 1) * WSTR + adr] = v.y;
      wsT[(kq * 4 + 2) * WSTR + adr] = v.z;
      wsT[(kq * 4 + 3) * WSTR + adr] = v.w;
    }
    __syncthreads();
#pragma unroll
    for (int k = 0; k < CK; ++k) {
      const float* xp = &xsT[k * XSTR + xoff];
      const float* wp = &wsT[k * WSTR + woff];
      floatx4 xa = *(const floatx4*)xp;
      floatx4 xb = *(const floatx4*)(xp + 4);
      floatx4 wa = *(const floatx4*)wp;
      floatx4 wb = *(const floatx4*)(wp + 4);
#pragma unroll
      for (int r = 0; r < 4; ++r)
#pragma unroll
        for (int e = 0; e < 4; ++e) {
          acc[r][e]         += xa[r] * wa[e];
          acc[r][e + 4]     += xa[r] * wb[e];
          acc[r + 4][e]     += xb[r] * wa[e];
          acc[r + 4][e + 4] += xb[r] * wb[e];
        }
    }
    __syncthreads();
  }
  // write partials: part[ks][row][e]
#pragma unroll
  for (int r = 0; r < 8; ++r) {
    float* pp = part + ((size_t)ks * NROWS + rbase + rg * 8 + r) * E_DIM + jc * 8;
    *(float4*)pp = make_float4(acc[r][0], acc[r][1], acc[r][2], acc[r][3]);
    *(float4*)(pp + 4) = make_float4(acc[r][4], acc[r][5], acc[r][6], acc[r][7]);
  }
}

// ---------------------------------------------------------------------------
// Kernel B: reduce 32 partial slices, add gumbel (k1), argmax over 64,
// write router one-hot + expert index.  1 wave/row; 4 rows/block.
// ---------------------------------------------------------------------------
__global__ __launch_bounds__(256) void krnB(const float* __restrict__ part,
                                            float* __restrict__ router_out,
                                            int* __restrict__ eidx,
                                            uint32_t K1A, uint32_t K1B) {
  const int t = threadIdx.x;
  const int wv = t >> 6, lane = t & 63;
  const int row = blockIdx.x * 4 + wv;
  float lg = 0.0f;
#pragma unroll
  for (int s = 0; s < KSPLIT; ++s)
    lg += part[((size_t)s * NROWS + row) * E_DIM + lane];

  uint32_t jf = (uint32_t)row * 64u + (uint32_t)lane;
  uint32_t bits = jax_bits32(K1A, K1B, jf);
  float u = jax_uniform(bits);
  float inner = -logf(u + 1e-20f);       // precise log: argmax sensitivity
  float g = -logf(inner + 1e-20f);
  float w = (lg + g) * 2.5f;

  float m = w;
#pragma unroll
  for (int off = 32; off >= 1; off >>= 1) m = fmaxf(m, __shfl_xor(m, off));
  unsigned long long msk = __ballot(w == m);
  int arg = __ffsll(msk) - 1;            // first max index == jnp.argmax
  router_out[(size_t)row * E_DIM + lane] = (lane == arg) ? 1.0f : 0.0f;
  if (lane == 0) eidx[row] = arg;
}

// ---------------------------------------------------------------------------
// Kernel C12 (fused C1+C2): per block recompute H = gelu(LN(rnn)) in LDS
// (trivial, 172x redundant), then P[e][m] = sum_c H[e][c]*Wd[m][c] and
// global min(P) via ordered-uint atomicMin.  pminKey needs NO init: the
// 0xAA poison decodes to a huge positive key, any real pmin wins, and even
// a garbage decode degrades safely through krnD's clamp (bit-exact, just
// slower fast-path).
// ---------------------------------------------------------------------------
__device__ inline uint32_t fkey(float f) {   // monotone float -> uint
  uint32_t b = __float_as_uint(f);
  return (b & 0x80000000u) ? ~b : (b | 0x80000000u);
}

__global__ __launch_bounds__(256) void krnC12(const float* __restrict__ rnn,
                                              const float* __restrict__ lnw,
                                              const float* __restrict__ lnb,
                                              const float* __restrict__ Wd,
                                              float* __restrict__ P,
                                              uint32_t* __restrict__ pminKey) {
  __shared__ __align__(16) float hsf[64 * EMB];   // 32 KB
  const int t = threadIdx.x;
  const int wv = t >> 6, lane = t & 63;
  // phase 1: LN + GELU, wave wv covers rows 16wv..16wv+15
  const float w0 = lnw[lane], w1 = lnw[lane + 64];
  const float b0 = lnb[lane], b1 = lnb[lane + 64];
  for (int rr = 0; rr < 16; ++rr) {
    const int r = wv * 16 + rr;
    float v0 = rnn[r * EMB + lane], v1 = rnn[r * EMB + 64 + lane];
    float s = v0 + v1;
#pragma unroll
    for (int off = 32; off >= 1; off >>= 1) s += __shfl_xor(s, off);
    float mu = s * (1.0f / 128.0f);
    float d0 = v0 - mu, d1 = v1 - mu;
    float q = d0 * d0 + d1 * d1;
#pragma unroll
    for (int off = 32; off >= 1; off >>= 1) q += __shfl_xor(q, off);
    float rs = rsqrtf(q * (1.0f / 128.0f) + 1e-5f);
    float h0 = d0 * rs * w0 + b0;
    float h1 = d1 * rs * w1 + b1;
    hsf[r * EMB + lane]      = 0.5f * h0 * (1.0f + erff(h0 * 0.70710678118654752f));
    hsf[r * EMB + 64 + lane] = 0.5f * h1 * (1.0f + erff(h1 * 0.70710678118654752f));
  }
  __syncthreads();
  // phase 2: GEMM, wave wv covers experts [16wv,16wv+16), lane -> m
  const int m = blockIdx.x * 64 + lane;
  const floatx4* wd4 = (const floatx4*)(Wd + (size_t)m * EMB);
  float acc[16] = {};
  for (int c4 = 0; c4 < 32; ++c4) {
    floatx4 w = wd4[c4];
#pragma unroll
    for (int e = 0; e < 16; ++e) {
      floatx4 h = *(const floatx4*)&hsf[(wv * 16 + e) * EMB + c4 * 4];
      acc[e] += w.x * h.x + w.y * h.y + w.z * h.z + w.w * h.w;
    }
  }
  float mn = acc[0];
#pragma unroll
  for (int e = 0; e < 16; ++e) {
    P[(size_t)(wv * 16 + e) * M_DIM + m] = acc[e];
    mn = fminf(mn, acc[e]);
  }
#pragma unroll
  for (int off = 32; off >= 1; off >>= 1)
    mn = fminf(mn, __shfl_xor(mn, off));
  if (lane == 0) atomicMin(pminKey, fkey(mn));
}

// ---------------------------------------------------------------------------
// Kernel D: 45M-element gumbel-sigmoid binarize with bits-space fast path.
// 4 elems/thread, ONE dwordx4 nt store per thread -> 16 B lane stride, fully
// dense wave stores (the 8-elem variant's 32 B-stride stores caused HBM
// write amplification: R6 +54 us).  Grid MUST be exactly BIN_N/1024 = 44032
// blocks (R7's 45056 overran d_out -> core dump).  Output is 0 only if
// u > 1 - exp(-exp(pre+3)); compare raw bits vs K9 from actual pmin with
// 0.05 gum-space slack (>> all fp error).  Rare lanes: exact chain.
// ---------------------------------------------------------------------------
__device__ inline float decide(float pre, uint32_t bits) {
  float u = jax_uniform(bits);
  float om = 1.0f - u;                 // exact for u >= 0.5 (Sterbenz)
  float e = -__logf(om);
  float gum = -__logf(e);              // e==0 -> +inf -> 1
  float z = pre + gum + 3.0f;
  return (z > 0.0f) ? 1.0f : 0.0f;
}

__global__ __launch_bounds__(256) void krnD(const float* __restrict__ P,
                                            const int* __restrict__ eidx,
                                            const uint32_t* __restrict__ pminKey,
                                            float* __restrict__ out,
                                            uint32_t K2A, uint32_t K2B) {
  // decode pmin, build bits-threshold (uniform across all threads)
  uint32_t kk = *pminKey;
  uint32_t pb = (kk & 0x80000000u) ? (kk ^ 0x80000000u) : ~kk;
  float pmin = __uint_as_float(pb);
  float tt = pmin + 2.95f;                       // 0.05 safety slack
  float delta = __expf(-__expf(tt));
  delta = fminf(fmaxf(delta, 1.2e-7f), 0.5f);    // NaN-safe, keeps Ku < 2^23
  uint32_t Ku = (uint32_t)((1.0f - delta) * 8388608.0f);
  uint32_t K9 = Ku << 9;

  uint32_t g = (blockIdx.x * 256u + threadIdx.x) * 4u;
  uint32_t b0 = jax_bits32(K2A, K2B, g + 0u);
  uint32_t b1 = jax_bits32(K2A, K2B, g + 1u);
  uint32_t b2 = jax_bits32(K2A, K2B, g + 2u);
  uint32_t b3 = jax_bits32(K2A, K2B, g + 3u);
  floatx4 r = {1.0f, 1.0f, 1.0f, 1.0f};
  uint32_t mx = max(max(b0, b1), max(b2, b3));
  if (mx >= K9) {                                // rare
    uint32_t row = g / (uint32_t)M_DIM;          // 4 elems share a row
    uint32_t m = g - row * (uint32_t)M_DIM;
    const float* pp = &P[(size_t)eidx[row] * M_DIM + m];
    if (b0 >= K9) r.x = decide(pp[0], b0);
    if (b1 >= K9) r.y = decide(pp[1], b1);
    if (b2 >= K9) r.z = decide(pp[2], b2);
    if (b3 >= K9) r.w = decide(pp[3], b3);
  }
  __builtin_nontemporal_store(r, (floatx4*)&out[g]);
}

// ---------------------------------------------------------------------------
extern "C" void kernel_launch(void* const* d_in, const int* in_sizes, int n_in,
                              void* d_out, int out_size, void* d_ws, size_t ws_size,
                              hipStream_t stream) {
  const float* x    = (const float*)d_in[0];
  const float* rnn  = (const float*)d_in[1];
  const float* Wr   = (const float*)d_in[2];
  const float* Wd   = (const float*)d_in[3];
  const float* lnw  = (const float*)d_in[4];
  const float* lnb  = (const float*)d_in[5];
  float* out = (float*)d_out;

  // k1, k2 = split(key(42)) -- foldlike split (verified round 3)
  uint32_t K1A, K1B, K2A, K2B;
  tf2x32(0u, 42u, 0u, 0u, K1A, K1B);
  tf2x32(0u, 42u, 0u, 1u, K2A, K2B);

  // workspace (ws): small buffers only.  Logit partials (33.5 MB) live in
  // the binary region of d_out, which krnD fully overwrites afterwards.
  char* ws = (char*)d_ws;
  int*      eidx    = (int*)ws;                       // 16 KB
  float*    P       = (float*)(ws + 65536);           // 2.82 MB (16B aligned)
  uint32_t* pminKey = (uint32_t*)(ws + 3276800);      // 4 B (poison-robust)

  float* part = out;                      // scratch inside binary region
  float* router_out = out + (size_t)BIN_N;

  krnC12<<<172, 256, 0, stream>>>(rnn, lnw, lnb, Wd, P, pminKey);
  krnA<<<dim3(16, KSPLIT), 256, 0, stream>>>(x, Wr, part);
  krnB<<<1024, 256, 0, stream>>>(part, router_out, eidx, K1A, K1B);
  krnD<<<44032, 256, 0, stream>>>(P, eidx, pminKey, out, K2A, K2B);  // exact
}

// Round 9
// 331.503 us; speedup vs baseline: 1.1690x; 1.1690x over previous
//
#include <hip/hip_runtime.h>
#include <hip/hip_bf16.h>
#include <stdint.h>

typedef float floatx4 __attribute__((ext_vector_type(4)));

// ---------------------------------------------------------------------------
// Threefry-2x32 (JAX-exact): 20 rounds, key injection every 4.
// ---------------------------------------------------------------------------
__host__ __device__ inline uint32_t rotl32(uint32_t x, int r) {
#ifdef __HIP_DEVICE_COMPILE__
  return __builtin_amdgcn_alignbit(x, x, 32 - r);
#else
  return (x << r) | (x >> (32 - r));
#endif
}

__host__ __device__ inline void tf2x32(uint32_t k0, uint32_t k1,
                                       uint32_t x0, uint32_t x1,
                                       uint32_t& o0, uint32_t& o1) {
  const uint32_t k2 = k0 ^ k1 ^ 0x1BD11BDAu;
  x0 += k0; x1 += k1;
#define TFR(r) { x0 += x1; x1 = rotl32(x1, r); x1 ^= x0; }
  TFR(13) TFR(15) TFR(26) TFR(6)
  x0 += k1; x1 += k2 + 1u;
  TFR(17) TFR(29) TFR(16) TFR(24)
  x0 += k2; x1 += k0 + 2u;
  TFR(13) TFR(15) TFR(26) TFR(6)
  x0 += k0; x1 += k1 + 3u;
  TFR(17) TFR(29) TFR(16) TFR(24)
  x0 += k1; x1 += k2 + 4u;
  TFR(13) TFR(15) TFR(26) TFR(6)
  x0 += k2; x1 += k0 + 5u;
#undef TFR
  o0 = x0; o1 = x1;
}

// Partitionable-mode 32-bit random bits, counts (0, i), bits = o0 ^ o1.
// [verified bit-exact vs np ref in rounds 3-8]
__device__ inline uint32_t jax_bits32(uint32_t kA, uint32_t kB, uint32_t i) {
  uint32_t o0, o1;
  tf2x32(kA, kB, 0u, i, o0, o1);
  return o0 ^ o1;
}

__device__ inline float jax_uniform(uint32_t bits) {
  return __uint_as_float((bits >> 9) | 0x3f800000u) - 1.0f;
}

#define D_DIM   4096
#define E_DIM   64
#define EMB     128
#define M_DIM   11008
#define NROWS   4096          // B*S
#define BIN_N   45088768      // NROWS*M_DIM
#define KSPLIT  32            // k-splits in krnA (each 128 wide)
#define CK      32            // staged k-chunk
#define XSTR    284           // R5-exact: 256 rows + quad-spread padding
#define WSTR    68            // R5-exact

// quad-spread address within a k-line: fragment f = v>>3 at f*8 + (f>>2)*4 so
// the 8 fragments of one wave's b128 read start in 8 distinct bank quads.
__device__ inline int qspread(int v) { return v + ((v >> 5) << 2); }

// ---------------------------------------------------------------------------
// Kernel A: logits partials, transposed-LDS outer-product fp32 GEMM.
// Grid (16 row-blocks, 32 k-splits) x 256 thr.  Block: 256 rows x 64 experts
// over 128 K.  Thread (jc=t&7, rg=t>>3): 8 rows x 8 experts, acc[8][8].
// ---------------------------------------------------------------------------
__global__ __launch_bounds__(256) void krnA(const float* __restrict__ x,
                                            const float* __restrict__ Wr,
                                            float* __restrict__ part) {
  __shared__ __align__(16) float xsT[CK * XSTR];   // 35.5 KB
  __shared__ __align__(16) float wsT[CK * WSTR];   // 8.5 KB
  const int rb = blockIdx.x, ks = blockIdx.y, t = threadIdx.x;
  const int rbase = rb * 256, kbase0 = ks * 128;
  const int jc = t & 7, rg = t >> 3;
  const int xoff = (rg * 8) + ((rg >> 2) << 2);    // qspread of rg*8
  const int woff = (jc * 8) + ((jc >> 2) << 2);
  float acc[8][8] = {};

  for (int c = 0; c < 4; ++c) {
    const int kbase = kbase0 + c * CK;
    // stage x: 256 rows x 32 k (8 float4 / thread, coalesced)
#pragma unroll
    for (int it = 0; it < 8; ++it) {
      int idx = t + it * 256;
      int row = idx >> 3, kq = idx & 7;
      float4 v = *(const float4*)&x[(size_t)(rbase + row) * D_DIM + kbase + kq * 4];
      int adr = qspread(row);
      xsT[(kq * 4 + 0) * XSTR + adr] = v.x;
      xsT[(kq * 4 + 1) * XSTR + adr] = v.y;
      xsT[(kq * 4 + 2) * XSTR + adr] = v.z;
      xsT[(kq * 4 + 3) * XSTR + adr] = v.w;
    }
    // stage Wr: 64 experts x 32 k (2 float4 / thread)
#pragma unroll
    for (int it = 0; it < 2; ++it) {
      int idx = t + it * 256;
      int e = idx >> 3, kq = idx & 7;
      float4 v = *(const float4*)&Wr[(size_t)e * D_DIM + kbase + kq * 4];
      int adr = qspread(e);
      wsT[(kq * 4 + 0) * WSTR + adr] = v.x;
      wsT[(kq * 4 + 1) * WSTR + adr] = v.y;
      wsT[(kq * 4 + 2) * WSTR + adr] = v.z;
      wsT[(kq * 4 + 3) * WSTR + adr] = v.w;
    }
    __syncthreads();
#pragma unroll
    for (int k = 0; k < CK; ++k) {
      const float* xp = &xsT[k * XSTR + xoff];
      const float* wp = &wsT[k * WSTR + woff];
      floatx4 xa = *(const floatx4*)xp;
      floatx4 xb = *(const floatx4*)(xp + 4);
      floatx4 wa = *(const floatx4*)wp;
      floatx4 wb = *(const floatx4*)(wp + 4);
#pragma unroll
      for (int r = 0; r < 4; ++r)
#pragma unroll
        for (int e = 0; e < 4; ++e) {
          acc[r][e]         += xa[r] * wa[e];
          acc[r][e + 4]     += xa[r] * wb[e];
          acc[r + 4][e]     += xb[r] * wa[e];
          acc[r + 4][e + 4] += xb[r] * wb[e];
        }
    }
    __syncthreads();
  }
  // write partials: part[ks][row][e]
#pragma unroll
  for (int r = 0; r < 8; ++r) {
    float* pp = part + ((size_t)ks * NROWS + rbase + rg * 8 + r) * E_DIM + jc * 8;
    *(float4*)pp = make_float4(acc[r][0], acc[r][1], acc[r][2], acc[r][3]);
    *(float4*)(pp + 4) = make_float4(acc[r][4], acc[r][5], acc[r][6], acc[r][7]);
  }
}

// ---------------------------------------------------------------------------
// Kernel B: reduce 32 partial slices, add gumbel (k1), argmax over 64,
// write router one-hot + expert index.  1 wave/row; 4 rows/block.
// ---------------------------------------------------------------------------
__global__ __launch_bounds__(256) void krnB(const float* __restrict__ part,
                                            float* __restrict__ router_out,
                                            int* __restrict__ eidx,
                                            uint32_t K1A, uint32_t K1B) {
  const int t = threadIdx.x;
  const int wv = t >> 6, lane = t & 63;
  const int row = blockIdx.x * 4 + wv;
  float lg = 0.0f;
#pragma unroll
  for (int s = 0; s < KSPLIT; ++s)
    lg += part[((size_t)s * NROWS + row) * E_DIM + lane];

  uint32_t jf = (uint32_t)row * 64u + (uint32_t)lane;
  uint32_t bits = jax_bits32(K1A, K1B, jf);
  float u = jax_uniform(bits);
  float inner = -logf(u + 1e-20f);       // precise log: argmax sensitivity
  float g = -logf(inner + 1e-20f);
  float w = (lg + g) * 2.5f;

  float m = w;
#pragma unroll
  for (int off = 32; off >= 1; off >>= 1) m = fmaxf(m, __shfl_xor(m, off));
  unsigned long long msk = __ballot(w == m);
  int arg = __ffsll(msk) - 1;            // first max index == jnp.argmax
  router_out[(size_t)row * E_DIM + lane] = (lane == arg) ? 1.0f : 0.0f;
  if (lane == 0) eidx[row] = arg;
}

// ---------------------------------------------------------------------------
// Kernel C1: H = gelu(layernorm(rnn_state)) + pminKey init.
// ---------------------------------------------------------------------------
__global__ __launch_bounds__(64) void krnC1(const float* __restrict__ rnn,
                                            const float* __restrict__ lnw,
                                            const float* __restrict__ lnb,
                                            float* __restrict__ H,
                                            uint32_t* __restrict__ pminKey) {
  const int r = blockIdx.x, lane = threadIdx.x;
  if (r == 0 && lane == 0) *pminKey = 0xFFFFFFFFu;
  float v0 = rnn[r * EMB + lane], v1 = rnn[r * EMB + 64 + lane];
  float s = v0 + v1;
#pragma unroll
  for (int off = 32; off >= 1; off >>= 1) s += __shfl_xor(s, off);
  float mu = s * (1.0f / 128.0f);
  float d0 = v0 - mu, d1 = v1 - mu;
  float q = d0 * d0 + d1 * d1;
#pragma unroll
  for (int off = 32; off >= 1; off >>= 1) q += __shfl_xor(q, off);
  float var = q * (1.0f / 128.0f);
  float rs = rsqrtf(var + 1e-5f);
  float h0 = d0 * rs * lnw[lane] + lnb[lane];
  float h1 = d1 * rs * lnw[lane + 64] + lnb[lane + 64];
  float g0 = 0.5f * h0 * (1.0f + erff(h0 * 0.70710678118654752f));
  float g1 = 0.5f * h1 * (1.0f + erff(h1 * 0.70710678118654752f));
  H[r * EMB + lane] = g0;
  H[r * EMB + 64 + lane] = g1;
}

// ---------------------------------------------------------------------------
// Kernel C2: P[e][m] = sum_c H[e][c]*Wd[m][c]  +  global min(P) via
// ordered-uint atomicMin (for krnD's fast-path threshold).
// ---------------------------------------------------------------------------
__device__ inline uint32_t fkey(float f) {   // monotone float -> uint
  uint32_t b = __float_as_uint(f);
  return (b & 0x80000000u) ? ~b : (b | 0x80000000u);
}

__global__ __launch_bounds__(256) void krnC2(const float* __restrict__ H,
                                             const float* __restrict__ Wd,
                                             float* __restrict__ P,
                                             uint32_t* __restrict__ pminKey) {
  __shared__ float4 hs[64][32];     // 32 KB
  const int t = threadIdx.x;
#pragma unroll
  for (int it = 0; it < 8; ++it) {
    int idx = t + it * 256;
    hs[idx >> 5][idx & 31] = ((const float4*)H)[idx];
  }
  __syncthreads();
  const int wv = t >> 6, lane = t & 63;
  const int m = blockIdx.x * 64 + lane;
  const float4* wd4 = (const float4*)(Wd + (size_t)m * EMB);
  float acc[16] = {};
  for (int c4 = 0; c4 < 32; ++c4) {
    float4 w = wd4[c4];
#pragma unroll
    for (int e = 0; e < 16; ++e) {
      float4 h = hs[wv * 16 + e][c4];
      acc[e] += w.x * h.x + w.y * h.y + w.z * h.z + w.w * h.w;
    }
  }
  float mn = acc[0];
#pragma unroll
  for (int e = 0; e < 16; ++e) {
    P[(size_t)(wv * 16 + e) * M_DIM + m] = acc[e];
    mn = fminf(mn, acc[e]);
  }
#pragma unroll
  for (int off = 32; off >= 1; off >>= 1)
    mn = fminf(mn, __shfl_xor(mn, off));
  if (lane == 0) atomicMin(pminKey, fkey(mn));
}

// ---------------------------------------------------------------------------
// Kernel D: 45M-element gumbel-sigmoid binarize with bits-space fast path.
// 4 elems/thread, ONE dwordx4 nt store -> dense wave stores.  Grid exactly
// BIN_N/1024 = 44032.  Output is 0 only if u > 1 - exp(-exp(pre+3));
// compare raw bits vs K9 from actual pmin with 0.05 gum-space slack.
// ---------------------------------------------------------------------------
__device__ inline float decide(float pre, uint32_t bits) {
  float u = jax_uniform(bits);
  float om = 1.0f - u;                 // exact for u >= 0.5 (Sterbenz)
  float e = -__logf(om);
  float gum = -__logf(e);              // e==0 -> +inf -> 1
  float z = pre + gum + 3.0f;
  return (z > 0.0f) ? 1.0f : 0.0f;
}

__global__ __launch_bounds__(256) void krnD(const float* __restrict__ P,
                                            const int* __restrict__ eidx,
                                            const uint32_t* __restrict__ pminKey,
                                            float* __restrict__ out,
                                            uint32_t K2A, uint32_t K2B) {
  // decode pmin, build bits-threshold (uniform across all threads)
  uint32_t kk = *pminKey;
  uint32_t pb = (kk & 0x80000000u) ? (kk ^ 0x80000000u) : ~kk;
  float pmin = __uint_as_float(pb);
  float tt = pmin + 2.95f;                       // 0.05 safety slack
  float delta = __expf(-__expf(tt));
  delta = fminf(fmaxf(delta, 1.2e-7f), 0.5f);    // NaN-safe, keeps Ku < 2^23
  uint32_t Ku = (uint32_t)((1.0f - delta) * 8388608.0f);
  uint32_t K9 = Ku << 9;

  uint32_t g = (blockIdx.x * 256u + threadIdx.x) * 4u;
  uint32_t b0 = jax_bits32(K2A, K2B, g + 0u);
  uint32_t b1 = jax_bits32(K2A, K2B, g + 1u);
  uint32_t b2 = jax_bits32(K2A, K2B, g + 2u);
  uint32_t b3 = jax_bits32(K2A, K2B, g + 3u);
  floatx4 r = {1.0f, 1.0f, 1.0f, 1.0f};
  uint32_t mx = max(max(b0, b1), max(b2, b3));
  if (mx >= K9) {                                // rare
    uint32_t row = g / (uint32_t)M_DIM;          // 4 elems share a row
    uint32_t m = g - row * (uint32_t)M_DIM;
    const float* pp = &P[(size_t)eidx[row] * M_DIM + m];
    if (b0 >= K9) r.x = decide(pp[0], b0);
    if (b1 >= K9) r.y = decide(pp[1], b1);
    if (b2 >= K9) r.z = decide(pp[2], b2);
    if (b3 >= K9) r.w = decide(pp[3], b3);
  }
  __builtin_nontemporal_store(r, (floatx4*)&out[g]);
}

// ---------------------------------------------------------------------------
extern "C" void kernel_launch(void* const* d_in, const int* in_sizes, int n_in,
                              void* d_out, int out_size, void* d_ws, size_t ws_size,
                              hipStream_t stream) {
  const float* x    = (const float*)d_in[0];
  const float* rnn  = (const float*)d_in[1];
  const float* Wr   = (const float*)d_in[2];
  const float* Wd   = (const float*)d_in[3];
  const float* lnw  = (const float*)d_in[4];
  const float* lnb  = (const float*)d_in[5];
  float* out = (float*)d_out;

  // k1, k2 = split(key(42)) -- foldlike split (verified round 3)
  uint32_t K1A, K1B, K2A, K2B;
  tf2x32(0u, 42u, 0u, 0u, K1A, K1B);
  tf2x32(0u, 42u, 0u, 1u, K2A, K2B);

  // workspace (ws): small buffers only.  Logit partials (33.5 MB) live in
  // the binary region of d_out, which krnD fully overwrites afterwards.
  char* ws = (char*)d_ws;
  int*      eidx    = (int*)ws;                       // 16 KB
  float*    H       = (float*)(ws + 16384);           // 32 KB
  float*    P       = (float*)(ws + 65536);           // 2.82 MB (16B aligned)
  uint32_t* pminKey = (uint32_t*)(ws + 3276800);      // 4 B

  float* part = out;                      // scratch inside binary region
  float* router_out = out + (size_t)BIN_N;

  krnA<<<dim3(16, KSPLIT), 256, 0, stream>>>(x, Wr, part);
  krnB<<<1024, 256, 0, stream>>>(part, router_out, eidx, K1A, K1B);
  krnC1<<<64, 64, 0, stream>>>(rnn, lnw, lnb, H, pminKey);
  krnC2<<<172, 256, 0, stream>>>(H, Wd, P, pminKey);
  krnD<<<44032, 256, 0, stream>>>(P, eidx, pminKey, out, K2A, K2B);
}